// Round 3
// baseline (167.602 us; speedup 1.0000x reference)
//
#include <hip/hip_runtime.h>

#define BSZ 64
#define SEQ 512
#define HD  768
#define TT  64     // topic/token list length
#define NPART 8    // blocks per batch
#define TPP 16     // topic/token tasks per part (64 / 4 parts)

// ---------------------------------------------------------------------------
// Fused kernel (round-1 structure, best measured: 162.95 us) + software
// pipelining of the task loop.
// grid = 64 batches x 8 parts = 512 blocks x 256 threads (4 waves/block).
//   part 0   : cls task + topic tasks l=0..15   (V rows 0..3 in LDS)
//   parts 1-3: topic tasks l=p*16..p*16+15      (V rows 2,3)
//   parts 4-7: token tasks l=(p-4)*16..+15      (V rows 4,5)
// Pipelining: first task's hidden-row float4 loads are issued BEFORE the dom
// barrier (they hide under the whole V-compute); inside the loop, task i+1's
// descriptor + hidden loads are issued before task i's reduce/store.
// ---------------------------------------------------------------------------
__global__ __launch_bounds__(256) void fused_kernel(
    const float* __restrict__ hidden,     // [64,512,768]
    const float* __restrict__ Wsrc,       // [862,384]
    const float* __restrict__ Wtgt,       // [862,384]
    const float* __restrict__ W_cls,      // [2,6144]
    const float* __restrict__ W_topic,    // [2,6144]
    const float* __restrict__ W_token,    // [2,6144]
    const float* __restrict__ b_cls,      // [2]
    const float* __restrict__ b_topic,    // [2]
    const float* __restrict__ b_token,    // [2]
    const int*   __restrict__ source_ids, // [64]
    const int*   __restrict__ target_ids, // [64]
    const int*   __restrict__ topic_inds, // [64,64]
    const float* __restrict__ topic_mask, // [64,64]
    const int*   __restrict__ token_inds, // [64,64]
    const float* __restrict__ token_mask, // [64,64]
    float*       __restrict__ out)        // [128 + 8192 + 8192]
{
    __shared__ __align__(16) float dom[HD];
    __shared__ __align__(16) float Vl[4][HD];   // 12 KB; +3 KB dom = 15 KB LDS

    const int blk = blockIdx.x;
    const int b   = blk >> 3;      // batch
    const int p   = blk & 7;       // part
    const int tid = threadIdx.x;
    const int wid  = tid >> 6;
    const int lane = tid & 63;
    const int ntasks = (p == 0) ? (1 + TPP) : TPP;

    // task descriptor: all loads are tiny/L2-hot
    auto task_params = [&](int ti, int& pos, float& mask, const float*& bias,
                           bool& sm, int& outoff, int& vbase) {
        if (p == 0 && ti == 0) {                    // cls
            pos = 0; mask = 1.f; bias = b_cls; sm = true;
            outoff = b * 2; vbase = 0;
        } else if (p < 4) {                         // topic
            const int l = (p == 0) ? (ti - 1) : (p * TPP + ti);
            pos = topic_inds[b * TT + l]; mask = topic_mask[b * TT + l];
            bias = b_topic; sm = true;
            outoff = 128 + (b * TT + l) * 2;
            vbase = (p == 0) ? 2 : 0;
        } else {                                    // token
            const int l = (p - 4) * TPP + ti;
            pos = token_inds[b * TT + l]; mask = token_mask[b * TT + l];
            bias = b_token; sm = false;
            outoff = 128 + BSZ * TT * 2 + (b * TT + l) * 2;
            vbase = 0;
        }
    };

    // ---- prefetch first task's hidden row (hides under dom+V compute) -----
    int pos, outoff, vbase; float mask; const float* bias; bool sm;
    float4 h0, h1, h2;
    const bool have_first = (wid < ntasks);
    if (have_first) {
        task_params(wid, pos, mask, bias, sm, outoff, vbase);
        const float4* hrow = reinterpret_cast<const float4*>(
            hidden + ((size_t)b * SEQ + (size_t)pos) * HD);
        h0 = hrow[lane]; h1 = hrow[lane + 64]; h2 = hrow[lane + 128];
    }

    // ---- stage domain embedding -------------------------------------------
    const int sid = source_ids[b];
    const int tgt = target_ids[b];
    for (int j = tid; j < HD; j += 256)
        dom[j] = (j < 384) ? Wsrc[sid * 384 + j] : Wtgt[tgt * 384 + (j - 384)];
    __syncthreads();

    // ---- compute the V rows this part needs into LDS ----------------------
    int base_row, nrows;
    if (p == 0)      { base_row = 0; nrows = 4; }   // cls (0,1) + topic (2,3)
    else if (p < 4)  { base_row = 2; nrows = 2; }   // topic
    else             { base_row = 4; nrows = 2; }   // token

    for (int idx = tid; idx < nrows * HD; idx += 256) {
        const int ri = idx / HD;
        const int d  = idx - ri * HD;
        const int r  = base_row + ri;               // global row id w*2+o
        const int w  = r >> 1, o = r & 1;
        const float* Wp = (w == 0) ? W_cls : (w == 1) ? W_topic : W_token;
        const int m = d >> 3, c = d & 7;
        const float* wrow = Wp + o * 6144 + m * 64 + c;
        float acc = 0.f;
        #pragma unroll
        for (int a = 0; a < 8; ++a)
            acc = fmaf(dom[m * 8 + a], wrow[a * 8], acc);
        Vl[ri][d] = acc;
    }
    __syncthreads();

    // ---- pipelined task loop ----------------------------------------------
    if (have_first) {
        int ti = wid;
        while (true) {
            // issue next task's descriptor + hidden loads before the reduce
            const int nti = ti + 4;
            const bool have_next = (nti < ntasks);
            int npos, noutoff, nvbase; float nmask; const float* nbias; bool nsm;
            float4 g0, g1, g2;
            if (have_next) {
                task_params(nti, npos, nmask, nbias, nsm, noutoff, nvbase);
                const float4* nhrow = reinterpret_cast<const float4*>(
                    hidden + ((size_t)b * SEQ + (size_t)npos) * HD);
                g0 = nhrow[lane]; g1 = nhrow[lane + 64]; g2 = nhrow[lane + 128];
            }

            const float4* v0 = reinterpret_cast<const float4*>(&Vl[vbase][0]);
            const float4* v1 = reinterpret_cast<const float4*>(&Vl[vbase + 1][0]);
            float a0 = 0.f, a1 = 0.f;
            {
                const float4 x0 = v0[lane],       y0 = v1[lane];
                const float4 x1 = v0[lane + 64],  y1 = v1[lane + 64];
                const float4 x2 = v0[lane + 128], y2 = v1[lane + 128];
                a0 = fmaf(h0.x, x0.x, a0); a1 = fmaf(h0.x, y0.x, a1);
                a0 = fmaf(h0.y, x0.y, a0); a1 = fmaf(h0.y, y0.y, a1);
                a0 = fmaf(h0.z, x0.z, a0); a1 = fmaf(h0.z, y0.z, a1);
                a0 = fmaf(h0.w, x0.w, a0); a1 = fmaf(h0.w, y0.w, a1);
                a0 = fmaf(h1.x, x1.x, a0); a1 = fmaf(h1.x, y1.x, a1);
                a0 = fmaf(h1.y, x1.y, a0); a1 = fmaf(h1.y, y1.y, a1);
                a0 = fmaf(h1.z, x1.z, a0); a1 = fmaf(h1.z, y1.z, a1);
                a0 = fmaf(h1.w, x1.w, a0); a1 = fmaf(h1.w, y1.w, a1);
                a0 = fmaf(h2.x, x2.x, a0); a1 = fmaf(h2.x, y2.x, a1);
                a0 = fmaf(h2.y, x2.y, a0); a1 = fmaf(h2.y, y2.y, a1);
                a0 = fmaf(h2.z, x2.z, a0); a1 = fmaf(h2.z, y2.z, a1);
                a0 = fmaf(h2.w, x2.w, a0); a1 = fmaf(h2.w, y2.w, a1);
            }
            #pragma unroll
            for (int off = 32; off > 0; off >>= 1) {
                a0 += __shfl_down(a0, off, 64);
                a1 += __shfl_down(a1, off, 64);
            }

            if (lane == 0) {
                const float l0 = fmaf(mask, a0, bias[0]);
                const float l1 = fmaf(mask, a1, bias[1]);
                if (sm) {
                    const float mx = fmaxf(l0, l1);
                    const float e0 = __expf(l0 - mx);
                    const float e1 = __expf(l1 - mx);
                    const float inv = 1.f / (e0 + e1);
                    out[outoff]     = e0 * inv;
                    out[outoff + 1] = e1 * inv;
                } else {
                    out[outoff]     = l0;
                    out[outoff + 1] = l1;
                }
            }

            if (!have_next) break;
            ti = nti;
            pos = npos; mask = nmask; bias = nbias; sm = nsm;
            outoff = noutoff; vbase = nvbase;
            h0 = g0; h1 = g1; h2 = g2;
        }
    }
}

extern "C" void kernel_launch(void* const* d_in, const int* in_sizes, int n_in,
                              void* d_out, int out_size, void* d_ws, size_t ws_size,
                              hipStream_t stream) {
    const float* hidden     = (const float*)d_in[0];
    const float* Wsrc       = (const float*)d_in[1];
    const float* Wtgt       = (const float*)d_in[2];
    const float* W_cls      = (const float*)d_in[3];
    const float* b_cls      = (const float*)d_in[4];
    const float* W_topic    = (const float*)d_in[5];
    const float* b_topic    = (const float*)d_in[6];
    const float* W_token    = (const float*)d_in[7];
    const float* b_token    = (const float*)d_in[8];
    const int*   source_ids = (const int*)d_in[9];
    const int*   target_ids = (const int*)d_in[10];
    // d_in[11] ent_inds, d_in[12] ent_mask: dead in reference (never used)
    const int*   topic_inds = (const int*)d_in[13];
    const float* topic_mask = (const float*)d_in[14];
    const int*   token_inds = (const int*)d_in[15];
    const float* token_mask = (const float*)d_in[16];
    float* out = (float*)d_out;

    fused_kernel<<<BSZ * NPART, 256, 0, stream>>>(
        hidden, Wsrc, Wtgt, W_cls, W_topic, W_token,
        b_cls, b_topic, b_token, source_ids, target_ids,
        topic_inds, topic_mask, token_inds, token_mask, out);
}